// Round 3
// baseline (209.339 us; speedup 1.0000x reference)
//
#include <hip/hip_runtime.h>
#include <hip/hip_bf16.h>

#define N_PIX 8192
#define C_DIM 128
#define HW 4096
// exp(dot/0.1) = exp2(dot * 14.42695...); fold sqrt of that into each vector.
#define PRESCALE 3.7982825f  // sqrt(log2(e)/0.1)
#define NUM_CLASSES 4

typedef __attribute__((ext_vector_type(8))) short short8;   // 8 x bf16 (4 VGPRs)
typedef __attribute__((ext_vector_type(4))) float float4v;  // 4 x f32 acc

// ---------------- Kernel 1: L2-normalize + prescale + bf16 cast; zero pos/tot ----------------
// 512 blocks x 256 threads; 16 pixels/block, 16 threads/pixel (8 channels each).
__global__ __launch_bounds__(256) void normscale_kernel(const float* __restrict__ emb,
                                                        unsigned short* __restrict__ ebf,
                                                        float* __restrict__ pz) {
    const int tid = threadIdx.x;
    const int p16 = tid & 15;   // pixel within block
    const int g = tid >> 4;     // channel group 0..15 (8 channels each)
    const int n = blockIdx.x * 16 + p16;
    const int b = n >> 12;
    const int hw = n & (HW - 1);
    const float* base = emb + b * (C_DIM * HW) + hw;

    float v[8];
    float ss = 0.f;
#pragma unroll
    for (int i = 0; i < 8; ++i) {
        v[i] = base[(g * 8 + i) * HW];
        ss += v[i] * v[i];
    }
    // reduce over channel groups: lanes differing in bits 4,5 share a pixel
    ss += __shfl_xor(ss, 16, 64);
    ss += __shfl_xor(ss, 32, 64);
    __shared__ float red[4][16];
    const int wv = tid >> 6;
    if ((tid & 63) < 16) red[wv][p16] = ss;
    __syncthreads();
    float tot = red[0][p16] + red[1][p16] + red[2][p16] + red[3][p16];
    float inv = PRESCALE / fmaxf(sqrtf(tot), 1e-12f);

    unsigned short us[8];
#pragma unroll
    for (int i = 0; i < 8; ++i) {
        __hip_bfloat16 h = __float2bfloat16(v[i] * inv);
        us[i] = *reinterpret_cast<unsigned short*>(&h);
    }
    *reinterpret_cast<short8*>(ebf + n * C_DIM + g * 8) = *reinterpret_cast<short8*>(us);

    // zero pos[8192]+tot[8192] (contiguous 16384 floats) using the first 64 blocks
    if (blockIdx.x < 64) pz[blockIdx.x * 256 + tid] = 0.f;
}

// ---------------- Kernel 2: fused S = e e^T (prescaled), exp2, masked row sums ----------------
// Grid (64 row-blocks x 32 j-splits) = 2048 blocks = exactly 8 blocks/CU. Block 256 = 4 waves.
// Wave: 32 rows (2 A-sets) x 256 cols (16 j-tiles).
__global__ __launch_bounds__(256, 8) void pairwise_kernel(const unsigned short* __restrict__ ebf,
                                                          const int* __restrict__ lab,
                                                          float* __restrict__ pos,
                                                          float* __restrict__ tot) {
    const int wave = threadIdx.x >> 6;
    const int lane = threadIdx.x & 63;
    const int quad = lane >> 4;
    const int lq = lane & 15;

    const int I0 = blockIdx.x * 128 + wave * 32;
    const int Jbase = blockIdx.y * 256;

    short8 afrag[2][4];
#pragma unroll
    for (int a = 0; a < 2; ++a) {
        const unsigned short* arow = ebf + (I0 + a * 16 + lq) * C_DIM + quad * 8;
#pragma unroll
        for (int s = 0; s < 4; ++s)
            afrag[a][s] = *reinterpret_cast<const short8*>(arow + s * 32);
    }
    int lab_row[2][4];
#pragma unroll
    for (int a = 0; a < 2; ++a)
#pragma unroll
        for (int r = 0; r < 4; ++r) lab_row[a][r] = lab[I0 + a * 16 + quad * 4 + r];

    float tacc[2][4] = {};
    float pacc[2][4] = {};

#define EPILOGUE(A, ACC, MASKED)                                            \
    {                                                                       \
        _Pragma("unroll") for (int r = 0; r < 4; ++r) {                     \
            float ex = __builtin_amdgcn_exp2f(ACC[r]);                      \
            if (MASKED) ex = (lq == quad * 4 + r) ? 0.f : ex;               \
            tacc[A][r] += ex;                                               \
            pacc[A][r] += (lab_row[A][r] == lab_col) ? ex : 0.f;            \
        }                                                                   \
    }

    for (int jt = 0; jt < 16; ++jt) {
        const int J = Jbase + jt * 16;
        const int lab_col = lab[J + lq];
        const unsigned short* brow = ebf + (J + lq) * C_DIM + quad * 8;
        short8 bfrag[4];
#pragma unroll
        for (int s = 0; s < 4; ++s)
            bfrag[s] = *reinterpret_cast<const short8*>(brow + s * 32);

        float4v acc0 = {0.f, 0.f, 0.f, 0.f};
        float4v acc1 = {0.f, 0.f, 0.f, 0.f};
#pragma unroll
        for (int s = 0; s < 4; ++s) {
            acc0 = __builtin_amdgcn_mfma_f32_16x16x32_bf16(afrag[0][s], bfrag[s], acc0, 0, 0, 0);
            acc1 = __builtin_amdgcn_mfma_f32_16x16x32_bf16(afrag[1][s], bfrag[s], acc1, 0, 0, 0);
        }
        // diagonal only possible when the 16-col tile coincides with a 16-row set (wave-uniform)
        if (J == I0) EPILOGUE(0, acc0, true) else EPILOGUE(0, acc0, false);
        if (J == I0 + 16) EPILOGUE(1, acc1, true) else EPILOGUE(1, acc1, false);
    }
#undef EPILOGUE

#pragma unroll
    for (int a = 0; a < 2; ++a) {
#pragma unroll
        for (int r = 0; r < 4; ++r) {
            float t = tacc[a][r], p = pacc[a][r];
#pragma unroll
            for (int off = 1; off < 16; off <<= 1) {
                t += __shfl_xor(t, off, 64);
                p += __shfl_xor(p, off, 64);
            }
            if (lq == 0) {
                const int row = I0 + a * 16 + quad * 4 + r;
                atomicAdd(&tot[row], t);
                atomicAdd(&pos[row], p);
            }
        }
    }
}

// ---------------- Kernel 3: row losses + per-class mean of means ----------------
__global__ __launch_bounds__(1024) void finalize_kernel(const float* __restrict__ pos,
                                                        const float* __restrict__ tot,
                                                        const int* __restrict__ lab,
                                                        float* __restrict__ out) {
    const int tid = threadIdx.x;
    float ls[NUM_CLASSES] = {0.f, 0.f, 0.f, 0.f};
    float lc[NUM_CLASSES] = {0.f, 0.f, 0.f, 0.f};
#pragma unroll
    for (int it = 0; it < N_PIX / 1024; ++it) {
        const int n = it * 1024 + tid;
        float rl = logf(tot[n] + 1e-6f) - logf(pos[n]);
        int c = lab[n];
#pragma unroll
        for (int k = 0; k < NUM_CLASSES; ++k) {
            if (c == k) {
                ls[k] += rl;
                lc[k] += 1.f;
            }
        }
    }
    // wave-level butterfly reduce of 8 values
#pragma unroll
    for (int off = 1; off < 64; off <<= 1) {
#pragma unroll
        for (int k = 0; k < NUM_CLASSES; ++k) {
            ls[k] += __shfl_xor(ls[k], off, 64);
            lc[k] += __shfl_xor(lc[k], off, 64);
        }
    }
    __shared__ float ssum[16][NUM_CLASSES];
    __shared__ float scnt[16][NUM_CLASSES];
    const int wid = tid >> 6;
    if ((tid & 63) == 0) {
#pragma unroll
        for (int k = 0; k < NUM_CLASSES; ++k) {
            ssum[wid][k] = ls[k];
            scnt[wid][k] = lc[k];
        }
    }
    __syncthreads();
    if (tid == 0) {
        float acc = 0.f;
        int present = 0;
        for (int k = 0; k < NUM_CLASSES; ++k) {
            float s = 0.f, c = 0.f;
            for (int w = 0; w < 16; ++w) {
                s += ssum[w][k];
                c += scnt[w][k];
            }
            if (c > 0.f) {
                acc += s / c;
                present++;
            }
        }
        out[0] = acc / (float)(present > 0 ? present : 1);
    }
}

extern "C" void kernel_launch(void* const* d_in, const int* in_sizes, int n_in,
                              void* d_out, int out_size, void* d_ws, size_t ws_size,
                              hipStream_t stream) {
    const float* emb = (const float*)d_in[0];  // [2,128,64,64] fp32
    const int* lab = (const int*)d_in[1];      // [2,64,64] int32
    float* out = (float*)d_out;

    unsigned short* ebf = (unsigned short*)d_ws;             // [8192][128] bf16 = 2 MiB
    float* pos = (float*)((char*)d_ws + N_PIX * C_DIM * 2);  // [8192] f32
    float* tot = pos + N_PIX;                                // [8192] f32 (contiguous after pos)

    normscale_kernel<<<N_PIX / 16, 256, 0, stream>>>(emb, ebf, pos);

    dim3 grid(N_PIX / 128, 32);  // 2048 blocks = 8 blocks/CU x 256 CU
    pairwise_kernel<<<grid, 256, 0, stream>>>(ebf, lab, pos, tot);

    finalize_kernel<<<1, 1024, 0, stream>>>(pos, tot, lab, out);
}

// Round 4
// 134.834 us; speedup vs baseline: 1.5526x; 1.5526x over previous
//
#include <hip/hip_runtime.h>
#include <hip/hip_bf16.h>

#define N_PIX 8192
#define C_DIM 128
#define HW 4096
// exp(dot/0.1) = exp2(dot * 14.42695...); fold sqrt of that into each vector.
#define PRESCALE 3.7982825f  // sqrt(log2(e)/0.1)
#define NUM_CLASSES 4

typedef __attribute__((ext_vector_type(8))) short short8;   // 8 x bf16 (4 VGPRs)
typedef __attribute__((ext_vector_type(4))) float float4v;  // 4 x f32 acc

// ---------------- Kernel 1: L2-normalize + prescale + bf16 cast; zero pos/tot ----------------
// 512 blocks x 256 threads; 16 pixels/block, 16 threads/pixel (8 channels each).
__global__ __launch_bounds__(256) void normscale_kernel(const float* __restrict__ emb,
                                                        unsigned short* __restrict__ ebf,
                                                        float* __restrict__ pz) {
    const int tid = threadIdx.x;
    const int p16 = tid & 15;   // pixel within block
    const int g = tid >> 4;     // channel group 0..15 (8 channels each)
    const int n = blockIdx.x * 16 + p16;
    const int b = n >> 12;
    const int hw = n & (HW - 1);
    const float* base = emb + b * (C_DIM * HW) + hw;

    float v[8];
    float ss = 0.f;
#pragma unroll
    for (int i = 0; i < 8; ++i) {
        v[i] = base[(g * 8 + i) * HW];
        ss += v[i] * v[i];
    }
    // reduce over channel groups: lanes differing in bits 4,5 share a pixel
    ss += __shfl_xor(ss, 16, 64);
    ss += __shfl_xor(ss, 32, 64);
    __shared__ float red[4][16];
    const int wv = tid >> 6;
    if ((tid & 63) < 16) red[wv][p16] = ss;
    __syncthreads();
    float tot = red[0][p16] + red[1][p16] + red[2][p16] + red[3][p16];
    float inv = PRESCALE / fmaxf(sqrtf(tot), 1e-12f);

    unsigned short us[8];
#pragma unroll
    for (int i = 0; i < 8; ++i) {
        __hip_bfloat16 h = __float2bfloat16(v[i] * inv);
        us[i] = *reinterpret_cast<unsigned short*>(&h);
    }
    *reinterpret_cast<short8*>(ebf + n * C_DIM + g * 8) = *reinterpret_cast<short8*>(us);

    // zero pos[8192]+tot[8192] (contiguous 16384 floats) using the first 64 blocks
    if (blockIdx.x < 64) pz[blockIdx.x * 256 + tid] = 0.f;
}

// ---------------- Kernel 2: fused S = e e^T (prescaled), exp2, masked row sums ----------------
// Grid (64 row-blocks x 32 j-splits) = 2048 blocks = 8 blocks/CU. Block 256 = 4 waves.
// Wave: 32 rows (2 A-sets) x 256 cols (16 j-tiles).
// NOTE: __launch_bounds__(256,4) — NOT (256,8): the 64-VGPR cap at 8 waves/EU
// spills afrag/bfrag to scratch (R3: VGPR 32, FETCH 79MB, 152us). At 52 VGPRs
// the HW grants 8 waves/EU anyway (<=64-reg occupancy step).
__global__ __launch_bounds__(256, 4) void pairwise_kernel(const unsigned short* __restrict__ ebf,
                                                          const int* __restrict__ lab,
                                                          float* __restrict__ pos,
                                                          float* __restrict__ tot) {
    const int wave = threadIdx.x >> 6;
    const int lane = threadIdx.x & 63;
    const int quad = lane >> 4;
    const int lq = lane & 15;

    const int I0 = blockIdx.x * 128 + wave * 32;
    const int Jbase = blockIdx.y * 256;

    short8 afrag[2][4];
#pragma unroll
    for (int a = 0; a < 2; ++a) {
        const unsigned short* arow = ebf + (I0 + a * 16 + lq) * C_DIM + quad * 8;
#pragma unroll
        for (int s = 0; s < 4; ++s)
            afrag[a][s] = *reinterpret_cast<const short8*>(arow + s * 32);
    }
    int lab_row[2][4];
#pragma unroll
    for (int a = 0; a < 2; ++a)
#pragma unroll
        for (int r = 0; r < 4; ++r) lab_row[a][r] = lab[I0 + a * 16 + quad * 4 + r];

    float tacc[2][4] = {};
    float pacc[2][4] = {};

#define EPILOGUE(A, ACC, MASKED)                                            \
    {                                                                       \
        _Pragma("unroll") for (int r = 0; r < 4; ++r) {                     \
            float ex = __builtin_amdgcn_exp2f(ACC[r]);                      \
            if (MASKED) ex = (lq == quad * 4 + r) ? 0.f : ex;               \
            tacc[A][r] += ex;                                               \
            pacc[A][r] += (lab_row[A][r] == lab_col) ? ex : 0.f;            \
        }                                                                   \
    }

    for (int jt = 0; jt < 16; ++jt) {
        const int J = Jbase + jt * 16;
        const int lab_col = lab[J + lq];
        const unsigned short* brow = ebf + (J + lq) * C_DIM + quad * 8;
        short8 bfrag[4];
#pragma unroll
        for (int s = 0; s < 4; ++s)
            bfrag[s] = *reinterpret_cast<const short8*>(brow + s * 32);

        float4v acc0 = {0.f, 0.f, 0.f, 0.f};
        float4v acc1 = {0.f, 0.f, 0.f, 0.f};
#pragma unroll
        for (int s = 0; s < 4; ++s) {
            acc0 = __builtin_amdgcn_mfma_f32_16x16x32_bf16(afrag[0][s], bfrag[s], acc0, 0, 0, 0);
            acc1 = __builtin_amdgcn_mfma_f32_16x16x32_bf16(afrag[1][s], bfrag[s], acc1, 0, 0, 0);
        }
        // diagonal only possible when the 16-col tile coincides with a 16-row set (wave-uniform)
        if (J == I0) EPILOGUE(0, acc0, true) else EPILOGUE(0, acc0, false);
        if (J == I0 + 16) EPILOGUE(1, acc1, true) else EPILOGUE(1, acc1, false);
    }
#undef EPILOGUE

#pragma unroll
    for (int a = 0; a < 2; ++a) {
#pragma unroll
        for (int r = 0; r < 4; ++r) {
            float t = tacc[a][r], p = pacc[a][r];
#pragma unroll
            for (int off = 1; off < 16; off <<= 1) {
                t += __shfl_xor(t, off, 64);
                p += __shfl_xor(p, off, 64);
            }
            if (lq == 0) {
                const int row = I0 + a * 16 + quad * 4 + r;
                atomicAdd(&tot[row], t);
                atomicAdd(&pos[row], p);
            }
        }
    }
}

// ---------------- Kernel 3: row losses + per-class mean of means ----------------
__global__ __launch_bounds__(1024) void finalize_kernel(const float* __restrict__ pos,
                                                        const float* __restrict__ tot,
                                                        const int* __restrict__ lab,
                                                        float* __restrict__ out) {
    const int tid = threadIdx.x;
    float ls[NUM_CLASSES] = {0.f, 0.f, 0.f, 0.f};
    float lc[NUM_CLASSES] = {0.f, 0.f, 0.f, 0.f};
#pragma unroll
    for (int it = 0; it < N_PIX / 1024; ++it) {
        const int n = it * 1024 + tid;
        float rl = logf(tot[n] + 1e-6f) - logf(pos[n]);
        int c = lab[n];
#pragma unroll
        for (int k = 0; k < NUM_CLASSES; ++k) {
            if (c == k) {
                ls[k] += rl;
                lc[k] += 1.f;
            }
        }
    }
    // wave-level butterfly reduce
#pragma unroll
    for (int off = 1; off < 64; off <<= 1) {
#pragma unroll
        for (int k = 0; k < NUM_CLASSES; ++k) {
            ls[k] += __shfl_xor(ls[k], off, 64);
            lc[k] += __shfl_xor(lc[k], off, 64);
        }
    }
    __shared__ float ssum[16][NUM_CLASSES];
    __shared__ float scnt[16][NUM_CLASSES];
    const int wid = tid >> 6;
    if ((tid & 63) == 0) {
#pragma unroll
        for (int k = 0; k < NUM_CLASSES; ++k) {
            ssum[wid][k] = ls[k];
            scnt[wid][k] = lc[k];
        }
    }
    __syncthreads();
    if (tid == 0) {
        float acc = 0.f;
        int present = 0;
        for (int k = 0; k < NUM_CLASSES; ++k) {
            float s = 0.f, c = 0.f;
            for (int w = 0; w < 16; ++w) {
                s += ssum[w][k];
                c += scnt[w][k];
            }
            if (c > 0.f) {
                acc += s / c;
                present++;
            }
        }
        out[0] = acc / (float)(present > 0 ? present : 1);
    }
}

extern "C" void kernel_launch(void* const* d_in, const int* in_sizes, int n_in,
                              void* d_out, int out_size, void* d_ws, size_t ws_size,
                              hipStream_t stream) {
    const float* emb = (const float*)d_in[0];  // [2,128,64,64] fp32
    const int* lab = (const int*)d_in[1];      // [2,64,64] int32
    float* out = (float*)d_out;

    unsigned short* ebf = (unsigned short*)d_ws;             // [8192][128] bf16 = 2 MiB
    float* pos = (float*)((char*)d_ws + N_PIX * C_DIM * 2);  // [8192] f32
    float* tot = pos + N_PIX;                                // [8192] f32 (contiguous after pos)

    normscale_kernel<<<N_PIX / 16, 256, 0, stream>>>(emb, ebf, pos);

    dim3 grid(N_PIX / 128, 32);  // 2048 blocks = 8 blocks/CU x 256 CU
    pairwise_kernel<<<grid, 256, 0, stream>>>(ebf, lab, pos, tot);

    finalize_kernel<<<1, 1024, 0, stream>>>(pos, tot, lab, out);
}